// Round 2
// baseline (475.823 us; speedup 1.0000x reference)
//
#include <hip/hip_runtime.h>
#include <cstddef>

#define NB 64
#define LL 512
#define HH 256
#define HD 128
#define NG 512
#define TI 16

typedef _Float16 half_t;
typedef _Float16 half8 __attribute__((ext_vector_type(8)));
typedef _Float16 half4 __attribute__((ext_vector_type(4)));
typedef float f32x4 __attribute__((ext_vector_type(4)));

#define MFMA16(a, b, c) __builtin_amdgcn_mfma_f32_16x16x32_f16((a), (b), (c), 0, 0, 0)

// LDS pitches (<=2-way bank aliasing, free on CDNA4)
#define FP 264   // sFeatb pitch (f16)
#define XP 518   // sXG pitch (f32): 4-row quad stride = 4*518 dw == 8 mod 32 -> <=2-way
#define HBP 136  // sHb pitch (f16)

__device__ __forceinline__ float sigm(float x)  { return 1.0f / (1.0f + __expf(-x)); }
__device__ __forceinline__ float tanhf_(float x){ return 2.0f / (1.0f + __expf(-2.0f * x)) - 1.0f; }

// ---- prep: cast weights to f16, bsum = b_ih + b_hh ----
__global__ void prep_weights(const float* __restrict__ Wih, const float* __restrict__ Whh,
                             const float* __restrict__ bih, const float* __restrict__ bhh,
                             half_t* __restrict__ WihH, half_t* __restrict__ WhhH,
                             float* __restrict__ bsum)
{
    const int idx = blockIdx.x * 256 + threadIdx.x;
    if (idx < NG * HH) WihH[idx] = (half_t)Wih[idx];
    if (idx < NG * HD) WhhH[idx] = (half_t)Whh[idx];
    if (idx < NG)      bsum[idx] = bih[idx] + bhh[idx];
}

__global__ __launch_bounds__(512, 6) void span_lstm_mfma(
    const float* __restrict__ feats, const half_t* __restrict__ WihH,
    const half_t* __restrict__ WhhH, const float* __restrict__ bsum,
    const float* __restrict__ W_tri, const float* __restrict__ b_tri,
    const int* __restrict__ lens, float* __restrict__ out)
{
    // LDS raw: sXG 41440 (sFeatb 10560 and sVal 512 aliased inside) + sHb 8704
    //          + sEmitP 4096 = 54240 B -> 54272 rounded -> 3 blocks/CU (162816 B).
    __shared__ __align__(16) float  sXG[20 * XP];
    __shared__ __align__(16) half_t sHb[2][16 * HBP];
    __shared__ __align__(16) float  sEmitP[4][2][TI][8];

    half_t* sFeatb = (half_t*)sXG;   // dead after A-frag hoist; sXG overwrites it
    float*  sVal   = (float*)sXG;    // [16][4][2]; live only after last sXG read

    const int tid = threadIdx.x;
    const int b  = blockIdx.x >> 5;
    const int i0 = (blockIdx.x & 31) * TI;
    const int lens_b = lens[b];

    const int lane = tid & 63, wv = tid >> 6;   // 8 waves
    const int lm = lane & 15;                   // m / n within 16-tile
    const int lq = lane >> 4;                   // quad
    const int jw = wv * 16;                     // this wave's hidden-column slice

    // ---- stage feats window (20 rows) as f16 ----
    for (int idx = tid; idx < 20 * 64; idx += 512) {
        const int p  = idx >> 6;
        const int k4 = (idx & 63) << 2;
        const int gp = i0 + p;
        float4 v = make_float4(0.f, 0.f, 0.f, 0.f);
        if (gp < LL) v = *(const float4*)(feats + ((size_t)b * LL + gp) * HH + k4);
        half4 hv = {(half_t)v.x, (half_t)v.y, (half_t)v.z, (half_t)v.w};
        *(half4*)(&sFeatb[p * FP + k4]) = hv;
    }
    __syncthreads();

    // ---- hoist A-frags (2 M-tiles x 8 K-frags) into registers ----
    half8 afr[2][8];
    #pragma unroll
    for (int mt = 0; mt < 2; ++mt)
        #pragma unroll
        for (int kf = 0; kf < 8; ++kf)
            afr[mt][kf] = *(const half8*)(&sFeatb[(16 * mt + lm) * FP + kf * 32 + lq * 8]);
    __syncthreads();   // all feats reads done before sXG overwrites the union

    // ---- phase 1: wave computes XG only for ITS gate columns (4 ta x 16 cols) ----
    // sXG is wave-private -> no barrier needed before the t-loop.
    #pragma unroll
    for (int ta = 0; ta < 4; ++ta) {
        const int gb = ta * HD + jw;
        const float bs = bsum[gb + lm];
        f32x4 acc0 = {0.f, 0.f, 0.f, 0.f}, acc1 = {0.f, 0.f, 0.f, 0.f};
        #pragma unroll
        for (int kf = 0; kf < 8; ++kf) {
            const half8 bfr = *(const half8*)(WihH + (size_t)(gb + lm) * HH + kf * 32 + lq * 8);
            acc0 = MFMA16(afr[0][kf], bfr, acc0);
            acc1 = MFMA16(afr[1][kf], bfr, acc1);
        }
        #pragma unroll
        for (int r = 0; r < 4; ++r)
            sXG[(lq * 4 + r) * XP + gb + lm] = acc0[r] + bs;
        if (lq == 0) {
            #pragma unroll
            for (int r = 0; r < 4; ++r)
                sXG[(16 + r) * XP + gb + lm] = acc1[r] + bs;
        }
    }

    // ---- Whh B-frags: 4 ta x 4 kf for this wave's 16 columns (64 VGPRs) ----
    half8 bf2[4][4];
    #pragma unroll
    for (int ta = 0; ta < 4; ++ta)
        #pragma unroll
        for (int kf = 0; kf < 4; ++kf)
            bf2[ta][kf] = *(const half8*)(WhhH + (size_t)(ta * HD + jw + lm) * HD
                                          + kf * 32 + lq * 8);

    const float wt0 = W_tri[jw + lm];
    const float wt1 = W_tri[HD + jw + lm];

    float cc4[4] = {0.f, 0.f, 0.f, 0.f};

    #pragma unroll
    for (int t = 0; t < 4; ++t) {
        float accg[4][4];
        if (t > 0) {
            half8 ah[4];
            #pragma unroll
            for (int kf = 0; kf < 4; ++kf)
                ah[kf] = *(const half8*)(&sHb[(t - 1) & 1][lm * HBP + kf * 32 + lq * 8]);
            #pragma unroll
            for (int ta = 0; ta < 4; ++ta) {
                f32x4 a = {0.f, 0.f, 0.f, 0.f};
                #pragma unroll
                for (int kf = 0; kf < 4; ++kf)
                    a = MFMA16(ah[kf], bf2[ta][kf], a);
                #pragma unroll
                for (int r = 0; r < 4; ++r) accg[ta][r] = a[r];
            }
        } else {
            #pragma unroll
            for (int ta = 0; ta < 4; ++ta)
                #pragma unroll
                for (int r = 0; r < 4; ++r) accg[ta][r] = 0.f;
        }
        // + XG (row s+t), wave-private columns
        #pragma unroll
        for (int ta = 0; ta < 4; ++ta)
            #pragma unroll
            for (int r = 0; r < 4; ++r)
                accg[ta][r] += sXG[(lq * 4 + r + t) * XP + ta * HD + jw + lm];

        // cell update (f32, in-lane)
        float hh[4];
        #pragma unroll
        for (int r = 0; r < 4; ++r) {
            const float ig = sigm(accg[0][r]);
            const float fg = sigm(accg[1][r]);
            const float gg = tanhf_(accg[2][r]);
            const float og = sigm(accg[3][r]);
            cc4[r] = fg * cc4[r] + ig * gg;
            hh[r]  = og * tanhf_(cc4[r]);
        }

        // publish new h (f16, double-buffered) — not needed after last step
        if (t < 3) {
            #pragma unroll
            for (int r = 0; r < 4; ++r)
                sHb[t & 1][(lq * 4 + r) * HBP + jw + lm] = (half_t)hh[r];
        }

        // ---- in-register emission partials: reduce over this wave's 16 j's ----
        #pragma unroll
        for (int r = 0; r < 4; ++r) {
            float e0 = hh[r] * wt0;
            float e1 = hh[r] * wt1;
            e0 += __shfl_xor(e0, 1);  e1 += __shfl_xor(e1, 1);
            e0 += __shfl_xor(e0, 2);  e1 += __shfl_xor(e1, 2);
            e0 += __shfl_xor(e0, 4);  e1 += __shfl_xor(e1, 4);
            e0 += __shfl_xor(e0, 8);  e1 += __shfl_xor(e1, 8);
            if (lm == 0) {
                sEmitP[t][0][lq * 4 + r][wv] = e0;
                sEmitP[t][1][lq * 4 + r][wv] = e1;
            }
        }

        __syncthreads();   // one barrier per step: sHb + sEmitP visibility (no stores to drain)
    }

    // ---- finalize: value per (span-row es, width w, tag) into sVal (aliases dead sXG) ----
    if (tid < 128) {
        const int es = tid & 15, tag = (tid >> 4) & 1, w = (tid >> 5) + 1;
        const int i = i0 + es;
        const int rem = lens_b - i;
        float e = 0.f;
        if (rem > 0 && (i + w - 1) < LL) {
            const int ts = (rem < w ? rem : w) - 1;   // selected step index (0-based)
            const float* pp = sEmitP[ts][tag][es];
            e = b_tri[tag];
            #pragma unroll
            for (int k = 0; k < 8; ++k) e += pp[k];
        }
        sVal[(es * 4 + (w - 1)) * 2 + tag] = e;
    }
    __syncthreads();

    // ---- merged zero+emission write of the block's whole 64 KB out slice ----
    // No trailing barrier: stores stream out and retire at kernel end.
    float* ob = out + ((size_t)b * LL + i0) * (LL * 2);
    #pragma unroll
    for (int k = 0; k < 8; ++k) {
        const int cg = k * 512 + tid;          // f32x4 chunk id; 256 chunks per row
        const int es = cg >> 8;
        const int c  = cg & 255;
        const int jlo = 2 * c;                 // chunk = {(jlo,t0),(jlo,t1),(jlo+1,t0),(jlo+1,t1)}
        const int i  = i0 + es;
        f32x4 v = {0.f, 0.f, 0.f, 0.f};
        const int w0 = jlo - i + 1;
        if ((unsigned)(w0 - 1) < 4u) {
            v.x = sVal[(es * 4 + (w0 - 1)) * 2 + 0];
            v.y = sVal[(es * 4 + (w0 - 1)) * 2 + 1];
        }
        const int w1 = w0 + 1;
        if ((unsigned)(w1 - 1) < 4u) {
            v.z = sVal[(es * 4 + (w1 - 1)) * 2 + 0];
            v.w = sVal[(es * 4 + (w1 - 1)) * 2 + 1];
        }
        *(f32x4*)(ob + (size_t)cg * 4) = v;
    }
}

extern "C" void kernel_launch(void* const* d_in, const int* in_sizes, int n_in,
                              void* d_out, int out_size, void* d_ws, size_t ws_size,
                              hipStream_t stream)
{
    const float* feats = (const float*)d_in[0];
    const float* W_ih  = (const float*)d_in[1];
    const float* W_hh  = (const float*)d_in[2];
    const float* b_ih  = (const float*)d_in[3];
    const float* b_hh  = (const float*)d_in[4];
    const float* W_tri = (const float*)d_in[5];
    const float* b_tri = (const float*)d_in[6];
    const int*   lens  = (const int*)d_in[7];
    float* out = (float*)d_out;

    // NOTE: no hipMemsetAsync — span_lstm_mfma writes its full output slice (zeros merged in).

    // ws layout: WihH (256 KB) | WhhH (128 KB) | bsum (2 KB)
    half_t* WihH = (half_t*)d_ws;
    half_t* WhhH = WihH + (size_t)NG * HH;
    float*  bsum = (float*)(WhhH + (size_t)NG * HD);

    prep_weights<<<(NG * HH + 255) / 256, 256, 0, stream>>>(W_ih, W_hh, b_ih, b_hh,
                                                            WihH, WhhH, bsum);
    span_lstm_mfma<<<NB * (LL / TI), 512, 0, stream>>>(feats, WihH, WhhH, bsum,
                                                       W_tri, b_tri, lens, out);
}

// Round 3
// 260.980 us; speedup vs baseline: 1.8232x; 1.8232x over previous
//
#include <hip/hip_runtime.h>
#include <cstddef>

#define NB 64
#define LL 512
#define HH 256
#define HD 128
#define NG 512
#define TI 16

typedef _Float16 half_t;
typedef _Float16 half8 __attribute__((ext_vector_type(8)));
typedef _Float16 half4 __attribute__((ext_vector_type(4)));
typedef float f32x4 __attribute__((ext_vector_type(4)));

#define MFMA16(a, b, c) __builtin_amdgcn_mfma_f32_16x16x32_f16((a), (b), (c), 0, 0, 0)

// LDS pitches (<=2-way bank aliasing, free on CDNA4)
#define FP 264   // sFeatb pitch (f16)
#define XP 518   // sXG pitch (f32): 4-row quad stride = 4*518 dw == 8 mod 32 -> <=2-way
#define HBP 136  // sHb pitch (f16)

__device__ __forceinline__ float sigm(float x)  { return 1.0f / (1.0f + __expf(-x)); }
__device__ __forceinline__ float tanhf_(float x){ return 2.0f / (1.0f + __expf(-2.0f * x)) - 1.0f; }

// ---- prep: cast weights to f16, bsum = b_ih + b_hh ----
__global__ void prep_weights(const float* __restrict__ Wih, const float* __restrict__ Whh,
                             const float* __restrict__ bih, const float* __restrict__ bhh,
                             half_t* __restrict__ WihH, half_t* __restrict__ WhhH,
                             float* __restrict__ bsum)
{
    const int idx = blockIdx.x * 256 + threadIdx.x;
    if (idx < NG * HH) WihH[idx] = (half_t)Wih[idx];
    if (idx < NG * HD) WhhH[idx] = (half_t)Whh[idx];
    if (idx < NG)      bsum[idx] = bih[idx] + bhh[idx];
}

// launch_bounds(512,4): 128 unified VGPR/AGPR per lane. The afr/bf2 fragment
// working set (~128 regs) lives in AGPRs at this budget; (512,6) spilled it to
// scratch in HBM (round-2 regression: +850 MB traffic). Do not raise waves/EU.
__global__ __launch_bounds__(512, 4) void span_lstm_mfma(
    const float* __restrict__ feats, const half_t* __restrict__ WihH,
    const half_t* __restrict__ WhhH, const float* __restrict__ bsum,
    const float* __restrict__ W_tri, const float* __restrict__ b_tri,
    const int* __restrict__ lens, float* __restrict__ out)
{
    // LDS raw: sFeatb 10560 (sVal 512 aliased) + sXG 41440 + sHb 8704
    //          + sEmitP 4096 = 64800 B -> 2 blocks/CU.
    // sFeatb is NOT aliased with sXG: no fence pins all 16 A-frags live at once.
    __shared__ __align__(16) half_t sFeatb[20 * FP];
    __shared__ __align__(16) float  sXG[20 * XP];
    __shared__ __align__(16) half_t sHb[2][16 * HBP];
    __shared__ __align__(16) float  sEmitP[4][2][TI][8];

    float* sVal = (float*)sFeatb;   // [16][4][2]; live only after the t-loop

    const int tid = threadIdx.x;
    const int b  = blockIdx.x >> 5;
    const int i0 = (blockIdx.x & 31) * TI;
    const int lens_b = lens[b];

    const int lane = tid & 63, wv = tid >> 6;   // 8 waves
    const int lm = lane & 15;                   // m / n within 16-tile
    const int lq = lane >> 4;                   // quad
    const int jw = wv * 16;                     // this wave's hidden-column slice

    // ---- stage feats window (20 rows) as f16 ----
    for (int idx = tid; idx < 20 * 64; idx += 512) {
        const int p  = idx >> 6;
        const int k4 = (idx & 63) << 2;
        const int gp = i0 + p;
        float4 v = make_float4(0.f, 0.f, 0.f, 0.f);
        if (gp < LL) v = *(const float4*)(feats + ((size_t)b * LL + gp) * HH + k4);
        half4 hv = {(half_t)v.x, (half_t)v.y, (half_t)v.z, (half_t)v.w};
        *(half4*)(&sFeatb[p * FP + k4]) = hv;
    }
    __syncthreads();

    // ---- phase 1: wave computes XG only for ITS gate columns (4 ta x 16 cols) ----
    // sXG is wave-private -> no barrier needed before the t-loop.
    {
        half8 afr[2][8];
        #pragma unroll
        for (int mt = 0; mt < 2; ++mt)
            #pragma unroll
            for (int kf = 0; kf < 8; ++kf)
                afr[mt][kf] = *(const half8*)(&sFeatb[(16 * mt + lm) * FP + kf * 32 + lq * 8]);

        #pragma unroll
        for (int ta = 0; ta < 4; ++ta) {
            const int gb = ta * HD + jw;
            const float bs = bsum[gb + lm];
            f32x4 acc0 = {0.f, 0.f, 0.f, 0.f}, acc1 = {0.f, 0.f, 0.f, 0.f};
            #pragma unroll
            for (int kf = 0; kf < 8; ++kf) {
                const half8 bfr = *(const half8*)(WihH + (size_t)(gb + lm) * HH + kf * 32 + lq * 8);
                acc0 = MFMA16(afr[0][kf], bfr, acc0);
                acc1 = MFMA16(afr[1][kf], bfr, acc1);
            }
            #pragma unroll
            for (int r = 0; r < 4; ++r)
                sXG[(lq * 4 + r) * XP + gb + lm] = acc0[r] + bs;
            if (lq == 0) {
                #pragma unroll
                for (int r = 0; r < 4; ++r)
                    sXG[(16 + r) * XP + gb + lm] = acc1[r] + bs;
            }
        }
    }

    // ---- Whh B-frags: 4 ta x 4 kf for this wave's 16 columns (64 regs, AGPR-backed) ----
    half8 bf2[4][4];
    #pragma unroll
    for (int ta = 0; ta < 4; ++ta)
        #pragma unroll
        for (int kf = 0; kf < 4; ++kf)
            bf2[ta][kf] = *(const half8*)(WhhH + (size_t)(ta * HD + jw + lm) * HD
                                          + kf * 32 + lq * 8);

    const float wt0 = W_tri[jw + lm];
    const float wt1 = W_tri[HD + jw + lm];

    float cc4[4] = {0.f, 0.f, 0.f, 0.f};

    #pragma unroll
    for (int t = 0; t < 4; ++t) {
        float accg[4][4];
        if (t > 0) {
            half8 ah[4];
            #pragma unroll
            for (int kf = 0; kf < 4; ++kf)
                ah[kf] = *(const half8*)(&sHb[(t - 1) & 1][lm * HBP + kf * 32 + lq * 8]);
            #pragma unroll
            for (int ta = 0; ta < 4; ++ta) {
                f32x4 a = {0.f, 0.f, 0.f, 0.f};
                #pragma unroll
                for (int kf = 0; kf < 4; ++kf)
                    a = MFMA16(ah[kf], bf2[ta][kf], a);
                #pragma unroll
                for (int r = 0; r < 4; ++r) accg[ta][r] = a[r];
            }
        } else {
            #pragma unroll
            for (int ta = 0; ta < 4; ++ta)
                #pragma unroll
                for (int r = 0; r < 4; ++r) accg[ta][r] = 0.f;
        }
        // + XG (row s+t), wave-private columns
        #pragma unroll
        for (int ta = 0; ta < 4; ++ta)
            #pragma unroll
            for (int r = 0; r < 4; ++r)
                accg[ta][r] += sXG[(lq * 4 + r + t) * XP + ta * HD + jw + lm];

        // cell update (f32, in-lane)
        float hh[4];
        #pragma unroll
        for (int r = 0; r < 4; ++r) {
            const float ig = sigm(accg[0][r]);
            const float fg = sigm(accg[1][r]);
            const float gg = tanhf_(accg[2][r]);
            const float og = sigm(accg[3][r]);
            cc4[r] = fg * cc4[r] + ig * gg;
            hh[r]  = og * tanhf_(cc4[r]);
        }

        // publish new h (f16, double-buffered) — not needed after last step
        if (t < 3) {
            #pragma unroll
            for (int r = 0; r < 4; ++r)
                sHb[t & 1][(lq * 4 + r) * HBP + jw + lm] = (half_t)hh[r];
        }

        // ---- in-register emission partials: reduce over this wave's 16 j's ----
        #pragma unroll
        for (int r = 0; r < 4; ++r) {
            float e0 = hh[r] * wt0;
            float e1 = hh[r] * wt1;
            e0 += __shfl_xor(e0, 1);  e1 += __shfl_xor(e1, 1);
            e0 += __shfl_xor(e0, 2);  e1 += __shfl_xor(e1, 2);
            e0 += __shfl_xor(e0, 4);  e1 += __shfl_xor(e1, 4);
            e0 += __shfl_xor(e0, 8);  e1 += __shfl_xor(e1, 8);
            if (lm == 0) {
                sEmitP[t][0][lq * 4 + r][wv] = e0;
                sEmitP[t][1][lq * 4 + r][wv] = e1;
            }
        }

        __syncthreads();   // one barrier per step: sHb + sEmitP visibility (no stores to drain)
    }

    // ---- finalize: value per (span-row es, width w, tag) into sVal (aliases dead sFeatb) ----
    if (tid < 128) {
        const int es = tid & 15, tag = (tid >> 4) & 1, w = (tid >> 5) + 1;
        const int i = i0 + es;
        const int rem = lens_b - i;
        float e = 0.f;
        if (rem > 0 && (i + w - 1) < LL) {
            const int ts = (rem < w ? rem : w) - 1;   // selected step index (0-based)
            const float* pp = sEmitP[ts][tag][es];
            e = b_tri[tag];
            #pragma unroll
            for (int k = 0; k < 8; ++k) e += pp[k];
        }
        sVal[(es * 4 + (w - 1)) * 2 + tag] = e;
    }
    __syncthreads();

    // ---- merged zero+emission write of the block's whole 64 KB out slice ----
    // No trailing barrier: stores stream out and retire at kernel end.
    float* ob = out + ((size_t)b * LL + i0) * (LL * 2);
    #pragma unroll
    for (int k = 0; k < 8; ++k) {
        const int cg = k * 512 + tid;          // f32x4 chunk id; 256 chunks per row
        const int es = cg >> 8;
        const int c  = cg & 255;
        const int jlo = 2 * c;                 // chunk = {(jlo,t0),(jlo,t1),(jlo+1,t0),(jlo+1,t1)}
        const int i  = i0 + es;
        f32x4 v = {0.f, 0.f, 0.f, 0.f};
        const int w0 = jlo - i + 1;
        if ((unsigned)(w0 - 1) < 4u) {
            v.x = sVal[(es * 4 + (w0 - 1)) * 2 + 0];
            v.y = sVal[(es * 4 + (w0 - 1)) * 2 + 1];
        }
        const int w1 = w0 + 1;
        if ((unsigned)(w1 - 1) < 4u) {
            v.z = sVal[(es * 4 + (w1 - 1)) * 2 + 0];
            v.w = sVal[(es * 4 + (w1 - 1)) * 2 + 1];
        }
        *(f32x4*)(ob + (size_t)cg * 4) = v;
    }
}

extern "C" void kernel_launch(void* const* d_in, const int* in_sizes, int n_in,
                              void* d_out, int out_size, void* d_ws, size_t ws_size,
                              hipStream_t stream)
{
    const float* feats = (const float*)d_in[0];
    const float* W_ih  = (const float*)d_in[1];
    const float* W_hh  = (const float*)d_in[2];
    const float* b_ih  = (const float*)d_in[3];
    const float* b_hh  = (const float*)d_in[4];
    const float* W_tri = (const float*)d_in[5];
    const float* b_tri = (const float*)d_in[6];
    const int*   lens  = (const int*)d_in[7];
    float* out = (float*)d_out;

    // NOTE: no hipMemsetAsync — span_lstm_mfma writes its full output slice (zeros merged in).

    // ws layout: WihH (256 KB) | WhhH (128 KB) | bsum (2 KB)
    half_t* WihH = (half_t*)d_ws;
    half_t* WhhH = WihH + (size_t)NG * HH;
    float*  bsum = (float*)(WhhH + (size_t)NG * HD);

    prep_weights<<<(NG * HH + 255) / 256, 256, 0, stream>>>(W_ih, W_hh, b_ih, b_hh,
                                                            WihH, WhhH, bsum);
    span_lstm_mfma<<<NB * (LL / TI), 512, 0, stream>>>(feats, WihH, WhhH, bsum,
                                                       W_tri, b_tri, lens, out);
}

// Round 4
// 259.083 us; speedup vs baseline: 1.8366x; 1.0073x over previous
//
#include <hip/hip_runtime.h>
#include <cstddef>

#define NB 64
#define LL 512
#define HH 256
#define HD 128
#define NG 512
#define TI 16

typedef _Float16 half_t;
typedef _Float16 half8 __attribute__((ext_vector_type(8)));
typedef _Float16 half4 __attribute__((ext_vector_type(4)));
typedef float f32x4 __attribute__((ext_vector_type(4)));

#define MFMA16(a, b, c) __builtin_amdgcn_mfma_f32_16x16x32_f16((a), (b), (c), 0, 0, 0)

// LDS pitches (<=2-way bank aliasing, free on CDNA4)
#define FP 264   // sFeatb pitch (f16)
#define XP 518   // sXG pitch (f32): lanes hit rows R..R+3 x 16 cols -> uniform 2-way
#define HBP 136  // sHb pitch (f16)
#define EP 17    // sE inner pitch (f32): 17*es distinct mod 32 -> <=2-way on finalize reads

__device__ __forceinline__ float sigm(float x)  { return 1.0f / (1.0f + __expf(-x)); }
__device__ __forceinline__ float tanhf_(float x){ return 2.0f / (1.0f + __expf(-2.0f * x)) - 1.0f; }

// 16-lane (DPP-row) sum on the VALU pipe: no DS ops, ~4cy/stage vs ~120cy shfl.
template <int CTRL>
__device__ __forceinline__ float dppadd(float x) {
    int v = __builtin_amdgcn_update_dpp(0, __float_as_int(x), CTRL, 0xF, 0xF, true);
    return x + __int_as_float(v);
}
__device__ __forceinline__ float row16_sum(float x) {
    x = dppadd<0xB1>(x);    // quad_perm [1,0,3,2]  (xor 1)
    x = dppadd<0x4E>(x);    // quad_perm [2,3,0,1]  (xor 2)
    x = dppadd<0x141>(x);   // row_half_mirror      (cross quad within 8)
    x = dppadd<0x140>(x);   // row_mirror           (cross 8s within 16)
    return x;
}

// ---- prep: cast weights to f16, bsum = b_ih + b_hh ----
__global__ void prep_weights(const float* __restrict__ Wih, const float* __restrict__ Whh,
                             const float* __restrict__ bih, const float* __restrict__ bhh,
                             half_t* __restrict__ WihH, half_t* __restrict__ WhhH,
                             float* __restrict__ bsum)
{
    const int idx = blockIdx.x * 256 + threadIdx.x;
    if (idx < NG * HH) WihH[idx] = (half_t)Wih[idx];
    if (idx < NG * HD) WhhH[idx] = (half_t)Whh[idx];
    if (idx < NG)      bsum[idx] = bih[idx] + bhh[idx];
}

// launch_bounds(512,4): 128 unified VGPR/AGPR per lane. (512,6) spilled the
// fragment set to scratch (round-2: +850 MB HBM). Do not raise waves/EU.
__global__ __launch_bounds__(512, 4) void span_lstm_mfma(
    const float* __restrict__ feats, const half_t* __restrict__ WihH,
    const half_t* __restrict__ WhhH, const float* __restrict__ bsum,
    const float* __restrict__ W_tri, const float* __restrict__ b_tri,
    const int* __restrict__ lens, float* __restrict__ out)
{
    // LDS raw: sFeatb 10560 (sVal 512 aliased) + sXG 41440 + sHb 8704 + sE 4352
    //        = 65056 B -> 2 blocks/CU.
    __shared__ __align__(16) half_t sFeatb[20 * FP];
    __shared__ __align__(16) float  sXG[20 * XP];
    __shared__ __align__(16) half_t sHb[2][16 * HBP];
    __shared__ __align__(16) float  sE[4][16 * EP];   // [ts][s*EP + wv*2 + tag]

    float* sVal = (float*)sFeatb;   // [16][4][2]; live only after the t-loop

    const int tid = threadIdx.x;
    const int b  = blockIdx.x >> 5;
    const int i0 = (blockIdx.x & 31) * TI;
    const int lens_b = lens[b];

    const int lane = tid & 63, wv = tid >> 6;   // 8 waves
    const int lm = lane & 15;                   // m / n within 16-tile (DPP row-local)
    const int lq = lane >> 4;                   // quad
    const int jw = wv * 16;                     // this wave's hidden-column slice

    // ---- stage feats window (20 rows) as f16 ----
    for (int idx = tid; idx < 20 * 64; idx += 512) {
        const int p  = idx >> 6;
        const int k4 = (idx & 63) << 2;
        const int gp = i0 + p;
        float4 v = make_float4(0.f, 0.f, 0.f, 0.f);
        if (gp < LL) v = *(const float4*)(feats + ((size_t)b * LL + gp) * HH + k4);
        half4 hv = {(half_t)v.x, (half_t)v.y, (half_t)v.z, (half_t)v.w};
        *(half4*)(&sFeatb[p * FP + k4]) = hv;
    }
    __syncthreads();

    // ---- phase 1: wave computes XG only for ITS gate columns (4 ta x 16 cols) ----
    // sXG is wave-private -> no barrier needed before the t-loop.
    {
        half8 afr[2][8];
        #pragma unroll
        for (int mt = 0; mt < 2; ++mt)
            #pragma unroll
            for (int kf = 0; kf < 8; ++kf)
                afr[mt][kf] = *(const half8*)(&sFeatb[(16 * mt + lm) * FP + kf * 32 + lq * 8]);

        #pragma unroll
        for (int ta = 0; ta < 4; ++ta) {
            const int gb = ta * HD + jw;
            const float bs = bsum[gb + lm];
            f32x4 acc0 = {0.f, 0.f, 0.f, 0.f}, acc1 = {0.f, 0.f, 0.f, 0.f};
            #pragma unroll
            for (int kf = 0; kf < 8; ++kf) {
                const half8 bfr = *(const half8*)(WihH + (size_t)(gb + lm) * HH + kf * 32 + lq * 8);
                acc0 = MFMA16(afr[0][kf], bfr, acc0);
                acc1 = MFMA16(afr[1][kf], bfr, acc1);
            }
            #pragma unroll
            for (int r = 0; r < 4; ++r)
                sXG[(lq * 4 + r) * XP + gb + lm] = acc0[r] + bs;
            if (lq == 0) {
                #pragma unroll
                for (int r = 0; r < 4; ++r)
                    sXG[(16 + r) * XP + gb + lm] = acc1[r] + bs;
            }
        }
    }

    // ---- Whh B-frags: 4 ta x 4 kf for this wave's 16 columns ----
    half8 bf2[4][4];
    #pragma unroll
    for (int ta = 0; ta < 4; ++ta)
        #pragma unroll
        for (int kf = 0; kf < 4; ++kf)
            bf2[ta][kf] = *(const half8*)(WhhH + (size_t)(ta * HD + jw + lm) * HD
                                          + kf * 32 + lq * 8);

    float cc4[4]   = {0.f, 0.f, 0.f, 0.f};
    float hhA[4][4];   // all 4 steps' h kept in f32 regs -> emission leaves the loop

    // ---- recurrence: minimal barrier-locked body (no emission work inside) ----
    #pragma unroll
    for (int t = 0; t < 4; ++t) {
        float accg[4][4];
        if (t > 0) {
            half8 ah[4];
            #pragma unroll
            for (int kf = 0; kf < 4; ++kf)
                ah[kf] = *(const half8*)(&sHb[(t - 1) & 1][lm * HBP + kf * 32 + lq * 8]);
            #pragma unroll
            for (int ta = 0; ta < 4; ++ta) {
                f32x4 a = {0.f, 0.f, 0.f, 0.f};
                #pragma unroll
                for (int kf = 0; kf < 4; ++kf)
                    a = MFMA16(ah[kf], bf2[ta][kf], a);
                #pragma unroll
                for (int r = 0; r < 4; ++r) accg[ta][r] = a[r];
            }
        } else {
            #pragma unroll
            for (int ta = 0; ta < 4; ++ta)
                #pragma unroll
                for (int r = 0; r < 4; ++r) accg[ta][r] = 0.f;
        }
        // + XG (row s+t), wave-private columns
        #pragma unroll
        for (int ta = 0; ta < 4; ++ta)
            #pragma unroll
            for (int r = 0; r < 4; ++r)
                accg[ta][r] += sXG[(lq * 4 + r + t) * XP + ta * HD + jw + lm];

        // cell update (f32, in-lane)
        #pragma unroll
        for (int r = 0; r < 4; ++r) {
            const float ig = sigm(accg[0][r]);
            const float fg = sigm(accg[1][r]);
            const float gg = tanhf_(accg[2][r]);
            const float og = sigm(accg[3][r]);
            cc4[r] = fg * cc4[r] + ig * gg;
            hhA[t][r] = og * tanhf_(cc4[r]);
        }

        if (t < 3) {
            #pragma unroll
            for (int r = 0; r < 4; ++r)
                sHb[t & 1][(lq * 4 + r) * HBP + jw + lm] = (half_t)hhA[t][r];
            __syncthreads();   // h visibility; t=3 publishes nothing -> no barrier
        }
    }

    // ---- emission, fully outside the barrier cadence: DPP row-sums, f32-exact ----
    {
        const float wt0 = W_tri[jw + lm];
        const float wt1 = W_tri[HD + jw + lm];
        #pragma unroll
        for (int ts = 0; ts < 4; ++ts)
            #pragma unroll
            for (int r = 0; r < 4; ++r) {
                float e0 = row16_sum(hhA[ts][r] * wt0);
                float e1 = row16_sum(hhA[ts][r] * wt1);
                if (lm == 0) {
                    float2 v = make_float2(e0, e1);
                    *(float2*)&sE[ts][(lq * 4 + r) * EP + wv * 2] = v;
                }
            }
    }
    __syncthreads();   // sE visible to finalize

    // ---- finalize: value per (span-row es, width w, tag) into sVal ----
    if (tid < 128) {
        const int es = tid & 15, tag = (tid >> 4) & 1, w = (tid >> 5) + 1;
        const int i = i0 + es;
        const int rem = lens_b - i;
        float e = 0.f;
        if (rem > 0 && (i + w - 1) < LL) {
            const int ts = (rem < w ? rem : w) - 1;   // selected step index (0-based)
            e = b_tri[tag];
            #pragma unroll
            for (int k = 0; k < 8; ++k) e += sE[ts][es * EP + k * 2 + tag];
        }
        sVal[(es * 4 + (w - 1)) * 2 + tag] = e;
    }
    __syncthreads();

    // ---- merged zero+emission write of the block's whole 64 KB out slice ----
    // No trailing barrier: stores stream out and retire at kernel end.
    float* ob = out + ((size_t)b * LL + i0) * (LL * 2);
    #pragma unroll
    for (int k = 0; k < 8; ++k) {
        const int cg = k * 512 + tid;          // f32x4 chunk id; 256 chunks per row
        const int es = cg >> 8;
        const int c  = cg & 255;
        const int jlo = 2 * c;                 // chunk = {(jlo,t0),(jlo,t1),(jlo+1,t0),(jlo+1,t1)}
        const int i  = i0 + es;
        f32x4 v = {0.f, 0.f, 0.f, 0.f};
        const int w0 = jlo - i + 1;
        if ((unsigned)(w0 - 1) < 4u) {
            v.x = sVal[(es * 4 + (w0 - 1)) * 2 + 0];
            v.y = sVal[(es * 4 + (w0 - 1)) * 2 + 1];
        }
        const int w1 = w0 + 1;
        if ((unsigned)(w1 - 1) < 4u) {
            v.z = sVal[(es * 4 + (w1 - 1)) * 2 + 0];
            v.w = sVal[(es * 4 + (w1 - 1)) * 2 + 1];
        }
        *(f32x4*)(ob + (size_t)cg * 4) = v;
    }
}

extern "C" void kernel_launch(void* const* d_in, const int* in_sizes, int n_in,
                              void* d_out, int out_size, void* d_ws, size_t ws_size,
                              hipStream_t stream)
{
    const float* feats = (const float*)d_in[0];
    const float* W_ih  = (const float*)d_in[1];
    const float* W_hh  = (const float*)d_in[2];
    const float* b_ih  = (const float*)d_in[3];
    const float* b_hh  = (const float*)d_in[4];
    const float* W_tri = (const float*)d_in[5];
    const float* b_tri = (const float*)d_in[6];
    const int*   lens  = (const int*)d_in[7];
    float* out = (float*)d_out;

    // NOTE: no hipMemsetAsync — span_lstm_mfma writes its full output slice (zeros merged in).

    // ws layout: WihH (256 KB) | WhhH (128 KB) | bsum (2 KB)
    half_t* WihH = (half_t*)d_ws;
    half_t* WhhH = WihH + (size_t)NG * HH;
    float*  bsum = (float*)(WhhH + (size_t)NG * HD);

    prep_weights<<<(NG * HH + 255) / 256, 256, 0, stream>>>(W_ih, W_hh, b_ih, b_hh,
                                                            WihH, WhhH, bsum);
    span_lstm_mfma<<<NB * (LL / TI), 512, 0, stream>>>(feats, WihH, WhhH, bsum,
                                                       W_tri, b_tri, lens, out);
}

// Round 5
// 251.414 us; speedup vs baseline: 1.8926x; 1.0305x over previous
//
#include <hip/hip_runtime.h>
#include <cstddef>

#define NB 64
#define LL 512
#define HH 256
#define HD 128
#define NG 512
#define TI 16

typedef _Float16 half_t;
typedef _Float16 half8 __attribute__((ext_vector_type(8)));
typedef _Float16 half4 __attribute__((ext_vector_type(4)));
typedef float f32x4 __attribute__((ext_vector_type(4)));

#define MFMA16(a, b, c) __builtin_amdgcn_mfma_f32_16x16x32_f16((a), (b), (c), 0, 0, 0)

// LDS pitches (<=2-way bank aliasing, free on CDNA4)
#define FP 264   // sFeatb pitch (f16)
#define XP 518   // sXG pitch (f32): lanes hit rows R..R+3 x 16 cols -> uniform 2-way
#define HBP 136  // sHb pitch (f16)
#define EP 17    // sE inner pitch (f32)

// fast gates: v_rcp_f32 (~1 ulp) instead of full-precision divide (~10 instr).
// Error ~1e-7 relative -- invisible next to the f16-weight absmax of 1.95e-3.
__device__ __forceinline__ float sigm(float x)  { return __builtin_amdgcn_rcpf(1.0f + __expf(-x)); }
__device__ __forceinline__ float tanhf_(float x){ return 2.0f * __builtin_amdgcn_rcpf(1.0f + __expf(-2.0f * x)) - 1.0f; }

// 16-lane (DPP-row) sum on the VALU pipe: no DS ops.
template <int CTRL>
__device__ __forceinline__ float dppadd(float x) {
    int v = __builtin_amdgcn_update_dpp(0, __float_as_int(x), CTRL, 0xF, 0xF, true);
    return x + __int_as_float(v);
}
__device__ __forceinline__ float row16_sum(float x) {
    x = dppadd<0xB1>(x);    // quad_perm [1,0,3,2]  (xor 1)
    x = dppadd<0x4E>(x);    // quad_perm [2,3,0,1]  (xor 2)
    x = dppadd<0x141>(x);   // row_half_mirror
    x = dppadd<0x140>(x);   // row_mirror
    return x;
}

// ---- prep: cast weights to f16, bsum = b_ih + b_hh ----
__global__ void prep_weights(const float* __restrict__ Wih, const float* __restrict__ Whh,
                             const float* __restrict__ bih, const float* __restrict__ bhh,
                             half_t* __restrict__ WihH, half_t* __restrict__ WhhH,
                             float* __restrict__ bsum)
{
    const int idx = blockIdx.x * 256 + threadIdx.x;
    if (idx < NG * HH) WihH[idx] = (half_t)Wih[idx];
    if (idx < NG * HD) WhhH[idx] = (half_t)Whh[idx];
    if (idx < NG)      bsum[idx] = bih[idx] + bhh[idx];
}

// launch_bounds(512,4): 128 unified VGPR/AGPR per lane. (512,6) spilled the
// fragment set to scratch (round-2: +850 MB HBM). Do not raise waves/EU.
__global__ __launch_bounds__(512, 4) void span_lstm_mfma(
    const float* __restrict__ feats, const half_t* __restrict__ WihH,
    const half_t* __restrict__ WhhH, const float* __restrict__ bsum,
    const float* __restrict__ W_tri, const float* __restrict__ b_tri,
    const int* __restrict__ lens, float* __restrict__ out)
{
    __shared__ __align__(16) half_t sFeatb[20 * FP];
    __shared__ __align__(16) float  sXG[20 * XP];
    __shared__ __align__(16) half_t sHb[2][16 * HBP];
    __shared__ __align__(16) float  sE[4][16 * EP];   // [ts][s*EP + wv*2 + tag]

    float* sVal = (float*)sFeatb;   // [16][4][2]; live only after the t-loop

    const int tid = threadIdx.x;
    const int b  = blockIdx.x >> 5;
    const int i0 = (blockIdx.x & 31) * TI;
    const int lens_b = lens[b];

    float* ob = out + ((size_t)b * LL + i0) * (LL * 2);

    // ---- dead-block fast path: i0 >= lens_b means every span here has
    // rem <= 0 -> row_mask = 0 -> output is all zeros. ~48% of blocks
    // (lens ~ U(1..512)) skip the whole LSTM and just stream 64 KB of zeros.
    if (i0 >= lens_b) {
        f32x4* ob4 = (f32x4*)ob;
        const f32x4 zz = {0.f, 0.f, 0.f, 0.f};
        #pragma unroll
        for (int k = 0; k < 8; ++k)
            ob4[k * 512 + tid] = zz;
        return;
    }

    const int lane = tid & 63, wv = tid >> 6;   // 8 waves
    const int lm = lane & 15;                   // m / n within 16-tile (DPP row-local)
    const int lq = lane >> 4;                   // quad
    const int jw = wv * 16;                     // this wave's hidden-column slice

    // ---- stage feats window (20 rows) as f16 ----
    for (int idx = tid; idx < 20 * 64; idx += 512) {
        const int p  = idx >> 6;
        const int k4 = (idx & 63) << 2;
        const int gp = i0 + p;
        float4 v = make_float4(0.f, 0.f, 0.f, 0.f);
        if (gp < LL) v = *(const float4*)(feats + ((size_t)b * LL + gp) * HH + k4);
        half4 hv = {(half_t)v.x, (half_t)v.y, (half_t)v.z, (half_t)v.w};
        *(half4*)(&sFeatb[p * FP + k4]) = hv;
    }
    __syncthreads();

    // ---- phase 1: wave computes XG only for ITS gate columns (4 ta x 16 cols) ----
    // sXG is wave-private -> no barrier needed before the t-loop.
    {
        half8 afr[2][8];
        #pragma unroll
        for (int mt = 0; mt < 2; ++mt)
            #pragma unroll
            for (int kf = 0; kf < 8; ++kf)
                afr[mt][kf] = *(const half8*)(&sFeatb[(16 * mt + lm) * FP + kf * 32 + lq * 8]);

        #pragma unroll
        for (int ta = 0; ta < 4; ++ta) {
            const int gb = ta * HD + jw;
            const float bs = bsum[gb + lm];
            f32x4 acc0 = {0.f, 0.f, 0.f, 0.f}, acc1 = {0.f, 0.f, 0.f, 0.f};
            #pragma unroll
            for (int kf = 0; kf < 8; ++kf) {
                const half8 bfr = *(const half8*)(WihH + (size_t)(gb + lm) * HH + kf * 32 + lq * 8);
                acc0 = MFMA16(afr[0][kf], bfr, acc0);
                acc1 = MFMA16(afr[1][kf], bfr, acc1);
            }
            #pragma unroll
            for (int r = 0; r < 4; ++r)
                sXG[(lq * 4 + r) * XP + gb + lm] = acc0[r] + bs;
            if (lq == 0) {
                #pragma unroll
                for (int r = 0; r < 4; ++r)
                    sXG[(16 + r) * XP + gb + lm] = acc1[r] + bs;
            }
        }
    }

    // ---- Whh B-frags: 4 ta x 4 kf for this wave's 16 columns ----
    half8 bf2[4][4];
    #pragma unroll
    for (int ta = 0; ta < 4; ++ta)
        #pragma unroll
        for (int kf = 0; kf < 4; ++kf)
            bf2[ta][kf] = *(const half8*)(WhhH + (size_t)(ta * HD + jw + lm) * HD
                                          + kf * 32 + lq * 8);

    float cc4[4]   = {0.f, 0.f, 0.f, 0.f};
    float hhA[4][4];   // all 4 steps' h kept in f32 regs -> emission leaves the loop

    // ---- recurrence: minimal barrier-locked body (no emission work inside) ----
    #pragma unroll
    for (int t = 0; t < 4; ++t) {
        float accg[4][4];
        if (t > 0) {
            half8 ah[4];
            #pragma unroll
            for (int kf = 0; kf < 4; ++kf)
                ah[kf] = *(const half8*)(&sHb[(t - 1) & 1][lm * HBP + kf * 32 + lq * 8]);
            #pragma unroll
            for (int ta = 0; ta < 4; ++ta) {
                f32x4 a = {0.f, 0.f, 0.f, 0.f};
                #pragma unroll
                for (int kf = 0; kf < 4; ++kf)
                    a = MFMA16(ah[kf], bf2[ta][kf], a);
                #pragma unroll
                for (int r = 0; r < 4; ++r) accg[ta][r] = a[r];
            }
        } else {
            #pragma unroll
            for (int ta = 0; ta < 4; ++ta)
                #pragma unroll
                for (int r = 0; r < 4; ++r) accg[ta][r] = 0.f;
        }
        // + XG (row s+t), wave-private columns
        #pragma unroll
        for (int ta = 0; ta < 4; ++ta)
            #pragma unroll
            for (int r = 0; r < 4; ++r)
                accg[ta][r] += sXG[(lq * 4 + r + t) * XP + ta * HD + jw + lm];

        // cell update (f32, in-lane)
        #pragma unroll
        for (int r = 0; r < 4; ++r) {
            const float ig = sigm(accg[0][r]);
            const float fg = sigm(accg[1][r]);
            const float gg = tanhf_(accg[2][r]);
            const float og = sigm(accg[3][r]);
            cc4[r] = fg * cc4[r] + ig * gg;
            hhA[t][r] = og * tanhf_(cc4[r]);
        }

        if (t < 3) {
            #pragma unroll
            for (int r = 0; r < 4; ++r)
                sHb[t & 1][(lq * 4 + r) * HBP + jw + lm] = (half_t)hhA[t][r];
            __syncthreads();   // h visibility; t=3 publishes nothing -> no barrier
        }
    }

    // ---- emission, fully outside the barrier cadence: DPP row-sums, f32-exact ----
    {
        const float wt0 = W_tri[jw + lm];
        const float wt1 = W_tri[HD + jw + lm];
        #pragma unroll
        for (int ts = 0; ts < 4; ++ts)
            #pragma unroll
            for (int r = 0; r < 4; ++r) {
                float e0 = row16_sum(hhA[ts][r] * wt0);
                float e1 = row16_sum(hhA[ts][r] * wt1);
                if (lm == 0) {
                    float2 v = make_float2(e0, e1);
                    *(float2*)&sE[ts][(lq * 4 + r) * EP + wv * 2] = v;
                }
            }
    }
    __syncthreads();   // sE visible to finalize

    // ---- finalize: value per (span-row es, width w, tag) into sVal ----
    if (tid < 128) {
        const int es = tid & 15, tag = (tid >> 4) & 1, w = (tid >> 5) + 1;
        const int i = i0 + es;
        const int rem = lens_b - i;
        float e = 0.f;
        if (rem > 0 && (i + w - 1) < LL) {
            const int ts = (rem < w ? rem : w) - 1;   // selected step index (0-based)
            e = b_tri[tag];
            #pragma unroll
            for (int k = 0; k < 8; ++k) e += sE[ts][es * EP + k * 2 + tag];
        }
        sVal[(es * 4 + (w - 1)) * 2 + tag] = e;
    }
    __syncthreads();

    // ---- merged zero+emission write of the block's whole 64 KB out slice ----
    // No trailing barrier: stores stream out and retire at kernel end.
    #pragma unroll
    for (int k = 0; k < 8; ++k) {
        const int cg = k * 512 + tid;          // f32x4 chunk id; 256 chunks per row
        const int es = cg >> 8;
        const int c  = cg & 255;
        const int jlo = 2 * c;                 // chunk = {(jlo,t0),(jlo,t1),(jlo+1,t0),(jlo+1,t1)}
        const int i  = i0 + es;
        f32x4 v = {0.f, 0.f, 0.f, 0.f};
        const int w0 = jlo - i + 1;
        if ((unsigned)(w0 - 1) < 4u) {
            v.x = sVal[(es * 4 + (w0 - 1)) * 2 + 0];
            v.y = sVal[(es * 4 + (w0 - 1)) * 2 + 1];
        }
        const int w1 = w0 + 1;
        if ((unsigned)(w1 - 1) < 4u) {
            v.z = sVal[(es * 4 + (w1 - 1)) * 2 + 0];
            v.w = sVal[(es * 4 + (w1 - 1)) * 2 + 1];
        }
        *(f32x4*)(ob + (size_t)cg * 4) = v;
    }
}

extern "C" void kernel_launch(void* const* d_in, const int* in_sizes, int n_in,
                              void* d_out, int out_size, void* d_ws, size_t ws_size,
                              hipStream_t stream)
{
    const float* feats = (const float*)d_in[0];
    const float* W_ih  = (const float*)d_in[1];
    const float* W_hh  = (const float*)d_in[2];
    const float* b_ih  = (const float*)d_in[3];
    const float* b_hh  = (const float*)d_in[4];
    const float* W_tri = (const float*)d_in[5];
    const float* b_tri = (const float*)d_in[6];
    const int*   lens  = (const int*)d_in[7];
    float* out = (float*)d_out;

    // NOTE: no hipMemsetAsync — span_lstm_mfma writes its full output slice (zeros merged in).

    // ws layout: WihH (256 KB) | WhhH (128 KB) | bsum (2 KB)
    half_t* WihH = (half_t*)d_ws;
    half_t* WhhH = WihH + (size_t)NG * HH;
    float*  bsum = (float*)(WhhH + (size_t)NG * HD);

    prep_weights<<<(NG * HH + 255) / 256, 256, 0, stream>>>(W_ih, W_hh, b_ih, b_hh,
                                                            WihH, WhhH, bsum);
    span_lstm_mfma<<<NB * (LL / TI), 512, 0, stream>>>(feats, WihH, WhhH, bsum,
                                                       W_tri, b_tri, lens, out);
}